// Round 5
// baseline (372.972 us; speedup 1.0000x reference)
//
#include <hip/hip_runtime.h>
#include <math.h>

#define BB 4096
#define LL 200
#define HH 32
#define RR 8      // rows per block in MLP kernel

// ---------------------------------------------------------------------------
// Kernel A: collapsed attention pooling (streaming). One wave per b.
//   c    = U_w^T a_l                       (b-independent 64-vec)
//   sl_l = leaky(x[l].c + U_b.a_l + gt + att_b)
//   y    = sum_l sl*x[l],  S = sum_l sl
//   V[h] = U_w[h].y + U_b[h]*S
//   states = relu(concat(n0*wg, V/total))  -> d_ws
// Main loop: batched groups of 4 float4 loads, double-buffered (4-8 in
// flight, issued back-to-back so the scheduler can't collapse the window).
// ---------------------------------------------------------------------------
__global__ __launch_bounds__(256) void stream_pool_kernel(
    const float* __restrict__ gs,
    const float* __restrict__ ls,
    const float* __restrict__ W_w, const float* __restrict__ W_b,
    const float* __restrict__ U_w, const float* __restrict__ U_b,
    const float* __restrict__ att_w, const float* __restrict__ att_b,
    float* __restrict__ states)
{
    __shared__ float c_lds[4 * 64];
    __shared__ float y_lds[4 * 64];

    const int tid  = threadIdx.x;
    const int lane = tid & 63;
    const int wid  = tid >> 6;
    const int b    = blockIdx.x * 4 + wid;

    const int h    = lane & 31;   // owned hidden unit (both halves)
    const int half = lane >> 5;   // d-half for 64-d dots
    const int q    = lane & 15;   // d-quad within l-group
    const int lg   = lane >> 4;   // l-group 0..3

    // ---- wg[h] = gs[b].W_w[h] + W_b[h]; halves split d, xor32 combine ----
    const float4* g4 = (const float4*)(gs + (size_t)b * 64);
    const float4* W4 = (const float4*)(W_w);
    float wg = (half == 0) ? W_b[h] : 0.f;
    #pragma unroll
    for (int dd = 0; dd < 8; ++dd) {
        float4 gv = g4[half * 8 + dd];
        float4 wv = W4[h * 16 + half * 8 + dd];
        wg += gv.x * wv.x + gv.y * wv.y + gv.z * wv.z + gv.w * wv.w;
    }
    wg += __shfl_xor(wg, 32);     // all lanes now hold wg[h]

    // ---- gt = wg.a_g ; t2 = wg.a_l (butterfly over h within 32-halves) ----
    float gt = wg * att_w[h];
    float t2 = wg * att_w[HH + h];
    #pragma unroll
    for (int m = 1; m < 32; m <<= 1) {
        gt += __shfl_xor(gt, m);
        t2 += __shfl_xor(t2, m);
    }
    const float attb = att_b[0];
    const float lin0 = gt + t2 + attb;
    const float s0   = (lin0 > 0.f) ? lin0 : 0.01f * lin0;

    // ---- c[d] = sum_h a_l[h]*U_w[h][d]  (lane owns d=lane) ----
    float c = 0.f;
    float ubal = 0.f;
    #pragma unroll
    for (int hh = 0; hh < HH; ++hh) {
        const float alh = att_w[HH + hh];        // uniform -> s_load
        c    += alh * U_w[hh * 64 + lane];       // coalesced, L1-hot
        ubal += alh * U_b[hh];
    }
    c_lds[wid * 64 + lane] = c;
    __syncthreads();
    const float4 cq = *(const float4*)&c_lds[wid * 64 + 4 * q];
    const float base = gt + ubal + attb;

    // ---- main stream: 50 float4-chunks, batch-4 double buffer ----
    const float4* xs = (const float4*)(ls + (size_t)b * (LL * 64));
    const int idx0 = lg * 16 + q;
    float4 yx = make_float4(0.f, 0.f, 0.f, 0.f);
    float Sacc = 0.f;

    float4 bufA[4], bufB[4];
    #pragma unroll
    for (int i = 0; i < 4; ++i) bufA[i] = xs[idx0 + i * 64];

    #pragma unroll                 // full unroll: guards are compile-time
    for (int g = 0; g < 13; ++g) {
        float4* curb = (g & 1) ? bufB : bufA;
        float4* nxtb = (g & 1) ? bufA : bufB;
        #pragma unroll
        for (int i = 0; i < 4; ++i) {       // issue next batch back-to-back
            const int t = (g + 1) * 4 + i;
            if (t < 50) nxtb[i] = xs[idx0 + t * 64];
        }
        #pragma unroll
        for (int i = 0; i < 4; ++i) {
            const int t = g * 4 + i;
            if (t < 50) {
                float4 X = curb[i];
                float p = X.x * cq.x + X.y * cq.y + X.z * cq.z + X.w * cq.w;
                p += __shfl_xor(p, 1);
                p += __shfl_xor(p, 2);
                p += __shfl_xor(p, 4);
                p += __shfl_xor(p, 8);      // 16-lane group dot: x[l].c
                const float linv = p + base;
                const float sl = (linv > 0.f) ? linv : 0.01f * linv;
                yx.x += sl * X.x;
                yx.y += sl * X.y;
                yx.z += sl * X.z;
                yx.w += sl * X.w;
                Sacc += sl;                 // same across the 16-lane group
            }
        }
    }

    // ---- combine the 4 l-groups ----
    #pragma unroll
    for (int m = 16; m < 64; m <<= 1) {
        yx.x += __shfl_xor(yx.x, m);
        yx.y += __shfl_xor(yx.y, m);
        yx.z += __shfl_xor(yx.z, m);
        yx.w += __shfl_xor(yx.w, m);
        Sacc += __shfl_xor(Sacc, m);
    }
    if (lane < 16) *(float4*)&y_lds[wid * 64 + 4 * q] = yx;
    __syncthreads();

    // ---- V[h] = U_w[h].y + U_b[h]*S ----
    float V = (half == 0) ? (U_b[h] * Sacc) : 0.f;
    const float4* U4 = (const float4*)U_w;
    const float4* y4 = (const float4*)&y_lds[wid * 64];
    #pragma unroll
    for (int dd = 0; dd < 8; ++dd) {
        float4 uv = U4[h * 16 + half * 8 + dd];
        float4 yv = y4[half * 8 + dd];
        V += uv.x * yv.x + uv.y * yv.y + uv.z * yv.z + uv.w * yv.w;
    }
    V += __shfl_xor(V, 32);        // all lanes hold full V[h]

    const float total = s0 + Sacc;
    const float n0    = s0 / total;
    const float outv  = (lane < 32) ? (n0 * wg) : (V / total);
    states[(size_t)b * 64 + lane] = fmaxf(outv, 0.f);
}

// ---------------------------------------------------------------------------
// Kernel B: MLP 64->256->256->8, relu/relu/sigmoid. RR=8 rows per block.
// R4 post-mortem fix: weight reads were per-lane-row gathers (64 cache lines
// per instruction through TA/L1). Now each k-chunk (32 cols) of the weight
// matrix is staged into LDS with 128B-coalesced global reads and a padded
// pitch-33 layout; compute reads hit banks (tid+d)%32 -> 2-way (free).
// Thread = output unit, acc[RR] in registers across chunks (no reductions).
// ---------------------------------------------------------------------------
__global__ __launch_bounds__(256) void mlp_kernel(
    const float* __restrict__ states,
    const float* __restrict__ l1_w, const float* __restrict__ l1_b,
    const float* __restrict__ l2_w, const float* __restrict__ l2_b,
    const float* __restrict__ l3_w, const float* __restrict__ l3_b,
    float* __restrict__ out)
{
    __shared__ float s_w[256 * 33];                  // 33.8 KB weight chunk
    __shared__ __align__(16) float s_x [RR * 64];
    __shared__ __align__(16) float s_a1[RR * 256];
    __shared__ __align__(16) float s_a2[RR * 260];   // pad: conflict-free l3

    const int tid = threadIdx.x;
    const int b0  = blockIdx.x * RR;

    // load states tile (RR*64 floats) via float4
    const float4* st4 = (const float4*)(states + (size_t)b0 * 64);
    if (tid < RR * 16) ((float4*)s_x)[tid] = st4[tid];

    float acc[RR];

    // ================= layer 1: K=64, 2 k-chunks of 32 =================
    {
        const float bias = l1_b[tid];
        #pragma unroll
        for (int r = 0; r < RR; ++r) acc[r] = bias;

        for (int kc = 0; kc < 2; ++kc) {
            __syncthreads();   // protect s_w reuse (and s_x on kc=0)
            // stage: rows j=0..255, cols kc*32..+31  (8 lanes per row-seg)
            #pragma unroll
            for (int i = 0; i < 8; ++i) {
                const int f   = tid + i * 256;       // 0..2047
                const int j   = f >> 3;
                const int sg  = f & 7;
                const float4 v = *(const float4*)(l1_w + j * 64 + kc * 32 + sg * 4);
                float* dst = &s_w[j * 33 + sg * 4];  // bank (j+4sg+i)%32: free
                dst[0] = v.x; dst[1] = v.y; dst[2] = v.z; dst[3] = v.w;
            }
            __syncthreads();
            // compute: thread owns unit tid
            #pragma unroll
            for (int d4 = 0; d4 < 8; ++d4) {
                const float w0 = s_w[tid * 33 + d4 * 4 + 0];
                const float w1 = s_w[tid * 33 + d4 * 4 + 1];
                const float w2 = s_w[tid * 33 + d4 * 4 + 2];
                const float w3 = s_w[tid * 33 + d4 * 4 + 3];
                #pragma unroll
                for (int r = 0; r < RR; ++r) {
                    const float4 xv = *(const float4*)&s_x[r * 64 + kc * 32 + d4 * 4];
                    acc[r] += w0 * xv.x + w1 * xv.y + w2 * xv.z + w3 * xv.w;
                }
            }
        }
        #pragma unroll
        for (int r = 0; r < RR; ++r)
            s_a1[r * 256 + tid] = fmaxf(acc[r], 0.f);
    }

    // ================= layer 2: K=256, 8 k-chunks of 32 =================
    {
        const float bias = l2_b[tid];
        #pragma unroll
        for (int r = 0; r < RR; ++r) acc[r] = bias;

        for (int kc = 0; kc < 8; ++kc) {
            __syncthreads();   // protect s_w reuse (and s_a1 on kc=0)
            #pragma unroll
            for (int i = 0; i < 8; ++i) {
                const int f   = tid + i * 256;
                const int j   = f >> 3;
                const int sg  = f & 7;
                const float4 v = *(const float4*)(l2_w + j * 256 + kc * 32 + sg * 4);
                float* dst = &s_w[j * 33 + sg * 4];
                dst[0] = v.x; dst[1] = v.y; dst[2] = v.z; dst[3] = v.w;
            }
            __syncthreads();
            #pragma unroll
            for (int d4 = 0; d4 < 8; ++d4) {
                const float w0 = s_w[tid * 33 + d4 * 4 + 0];
                const float w1 = s_w[tid * 33 + d4 * 4 + 1];
                const float w2 = s_w[tid * 33 + d4 * 4 + 2];
                const float w3 = s_w[tid * 33 + d4 * 4 + 3];
                #pragma unroll
                for (int r = 0; r < RR; ++r) {
                    const float4 av = *(const float4*)&s_a1[r * 256 + kc * 32 + d4 * 4];
                    acc[r] += w0 * av.x + w1 * av.y + w2 * av.z + w3 * av.w;
                }
            }
        }
        #pragma unroll
        for (int r = 0; r < RR; ++r)
            s_a2[r * 260 + tid] = fmaxf(acc[r], 0.f);
    }
    __syncthreads();

    // ================= layer 3 + sigmoid: threads 0..RR*8-1 =================
    if (tid < RR * 8) {
        const int r = tid >> 3, o = tid & 7;
        float a = l3_b[o];
        const float4* wr4 = (const float4*)(l3_w + o * 256);
        const float4* a4  = (const float4*)&s_a2[r * 260];
        #pragma unroll 8
        for (int k = 0; k < 64; ++k) {
            const float4 av = a4[k];
            const float4 wv = wr4[k];
            a += av.x * wv.x + av.y * wv.y + av.z * wv.z + av.w * wv.w;
        }
        out[(size_t)(b0 + r) * 8 + o] = 1.f / (1.f + __expf(-a)); // MAX_ACTION=1
    }
}

// ---------------------------------------------------------------------------
extern "C" void kernel_launch(void* const* d_in, const int* in_sizes, int n_in,
                              void* d_out, int out_size, void* d_ws, size_t ws_size,
                              hipStream_t stream)
{
    const float* gs    = (const float*)d_in[0];
    const float* ls    = (const float*)d_in[1];
    const float* W_w   = (const float*)d_in[2];
    const float* W_b   = (const float*)d_in[3];
    const float* U_w   = (const float*)d_in[4];
    const float* U_b   = (const float*)d_in[5];
    const float* att_w = (const float*)d_in[6];
    const float* att_b = (const float*)d_in[7];
    const float* l1_w  = (const float*)d_in[8];
    const float* l1_b  = (const float*)d_in[9];
    const float* l2_w  = (const float*)d_in[10];
    const float* l2_b  = (const float*)d_in[11];
    const float* l3_w  = (const float*)d_in[12];
    const float* l3_b  = (const float*)d_in[13];

    float* states = (float*)d_ws;            // B*64 floats = 1 MB scratch

    stream_pool_kernel<<<BB / 4, 256, 0, stream>>>(
        gs, ls, W_w, W_b, U_w, U_b, att_w, att_b, states);
    mlp_kernel<<<BB / RR, 256, 0, stream>>>(
        states, l1_w, l1_b, l2_w, l2_b, l3_w, l3_b, (float*)d_out);
}

// Round 6
// 362.008 us; speedup vs baseline: 1.0303x; 1.0303x over previous
//
#include <hip/hip_runtime.h>
#include <math.h>

#define BB 4096
#define LL 200
#define HH 32
#define PITCH 65   // 65%32==1 -> conflict-free for row reads AND column reads
#define RR 8       // rows per block in MLP kernel

// ---------------------------------------------------------------------------
// Kernel A: collapsed attention pooling. ONE BLOCK PER b.
// R5 post-mortem: per-iteration load->shfl-chain consumption serialized every
// wave to ~1 outstanding load (830 GB/s ceiling across all prefetch depths).
// Fix: each thread issues its entire share of the 51.2 KB tile as 13
// INDEPENDENT float4 loads (no consumer between them -> one vmcnt drain),
// stages to LDS, and all hot-loop compute is LDS-side with no shuffles.
//   c    = U_w^T a_l                        (64-vec)
//   sl_l = leaky(x[l].c + U_b.a_l + gt + att_b)
//   y    = sum_l sl*x[l],  S = sum_l sl
//   V[h] = U_w[h].y + U_b[h]*S
//   states = relu(concat(n0*wg, V/total))
// ---------------------------------------------------------------------------
__global__ __launch_bounds__(256) void pool_kernel(
    const float* __restrict__ gs,
    const float* __restrict__ ls,
    const float* __restrict__ W_w, const float* __restrict__ W_b,
    const float* __restrict__ U_w, const float* __restrict__ U_b,
    const float* __restrict__ att_w, const float* __restrict__ att_b,
    float* __restrict__ states)
{
    __shared__ float xT[LL * PITCH];     // 52000 B
    __shared__ float sl_s[LL];           // 800 B
    __shared__ float ypart[4][64];       // 1024 B
    __shared__ float wg_s[HH];
    __shared__ float c_s[64];
    __shared__ float V_s[HH];
    __shared__ float misc[4];            // [0]=ubal [1]=gt [2]=s0 [3]=S

    const int tid = threadIdx.x;
    const int b   = blockIdx.x;

    // ---- issue the whole 51.2 KB tile: 13 independent float4 loads ----
    const float4* src = (const float4*)(ls + (size_t)b * (LL * 64));
    float4 v[13];
    #pragma unroll
    for (int k = 0; k < 13; ++k) {
        const int f = tid + (k << 8);
        if (f < LL * 16) v[k] = src[f];          // coalesced 4 KB per wave-instr
    }

    // ---- while tile is in flight: c[d], ubal (wave 0) and wg[h] (wave 1) ----
    const float attb = att_b[0];
    if (tid < 64) {
        float cacc = 0.f, ub = 0.f;
        #pragma unroll
        for (int hh = 0; hh < HH; ++hh) {
            const float alh = att_w[HH + hh];    // uniform -> s_load
            cacc += alh * U_w[hh * 64 + tid];    // coalesced, L2-hot
            ub   += alh * U_b[hh];
        }
        c_s[tid] = cacc;
        if (tid == 0) misc[0] = ub;
    } else if (tid < 96) {
        const int h = tid - 64;
        float acc = W_b[h];
        const float* g = gs + (size_t)b * 64;
        #pragma unroll
        for (int d = 0; d < 64; ++d)
            acc += g[d] * W_w[h * 64 + d];       // g[d] uniform -> s_load
        wg_s[h] = acc;
    }

    // ---- drain loads once, write tile to LDS (pitch 65, ~2-way free) ----
    #pragma unroll
    for (int k = 0; k < 13; ++k) {
        const int f = tid + (k << 8);
        if (f < LL * 16) {
            const int l  = f >> 4;
            const int c4 = (f & 15) << 2;
            float* dst = &xT[l * PITCH + c4];
            dst[0] = v[k].x; dst[1] = v[k].y; dst[2] = v[k].z; dst[3] = v[k].w;
        }
    }
    __syncthreads();

    // ---- gt, s0 (thread 0; ~130 cyc, off the critical stream) ----
    if (tid == 0) {
        float gt = 0.f, t2 = 0.f;
        #pragma unroll
        for (int h = 0; h < HH; ++h) {
            gt += wg_s[h] * att_w[h];
            t2 += wg_s[h] * att_w[HH + h];
        }
        const float lin0 = gt + t2 + attb;
        misc[1] = gt;
        misc[2] = (lin0 > 0.f) ? lin0 : 0.01f * lin0;
    }
    __syncthreads();

    // ---- sl[l]: thread t owns row l=t (banks (t+d)%32 -> free) ----
    if (tid < LL) {
        const float* row = &xT[tid * PITCH];
        float p = 0.f;
        #pragma unroll 16
        for (int d = 0; d < 64; ++d)
            p += row[d] * c_s[d];                // c_s[d] broadcast (free)
        const float lin = p + misc[1] + misc[0] + attb;
        sl_s[tid] = (lin > 0.f) ? lin : 0.01f * lin;
    }
    __syncthreads();

    // ---- y[d] partials: wave-uniform l -> sl broadcast + conflict-free x ----
    {
        const int qd = tid >> 6;                 // 0..3 (l-quarter)
        const int d  = tid & 63;
        float yp = 0.f;
        #pragma unroll 10
        for (int i = 0; i < 50; ++i) {
            const int l = qd * 50 + i;
            yp += sl_s[l] * xT[l * PITCH + d];
        }
        ypart[qd][d] = yp;
    }
    // wave 0 also computes S = sum_l sl (butterfly)
    if (tid < 64) {
        float sp = sl_s[tid] + sl_s[tid + 64] + sl_s[tid + 128];
        if (tid < 8) sp += sl_s[tid + 192];
        #pragma unroll
        for (int m = 1; m < 64; m <<= 1)
            sp += __shfl_xor(sp, m);
        if (tid == 0) misc[3] = sp;
    }
    __syncthreads();

    // ---- epilogue in wave 0 ----
    if (tid < 64) {
        const float yd = ypart[0][tid] + ypart[1][tid] +
                         ypart[2][tid] + ypart[3][tid];
        ypart[0][tid] = yd;                      // same-wave lockstep reuse
        const float S = misc[3];
        if (tid < HH) {
            float V = U_b[tid] * S;
            #pragma unroll 8
            for (int d = 0; d < 64; ++d)
                V += U_w[tid * 64 + d] * ypart[0][d];   // L1-hot gather
            V_s[tid] = V;
        }
        const float s0    = misc[2];
        const float total = s0 + S;
        const float outv  = (tid < HH) ? ((s0 / total) * wg_s[tid])
                                       : (V_s[tid - HH] / total);
        states[(size_t)b * 64 + tid] = fmaxf(outv, 0.f);
    }
}

// ---------------------------------------------------------------------------
// Kernel B: MLP 64->256->256->8, relu/relu/sigmoid. RR=8 rows per block.
// Weights staged into LDS per k-chunk with 128B-coalesced reads; compute
// reads are 2-way (free) bank-aliased; acc[RR] in registers.
// ---------------------------------------------------------------------------
__global__ __launch_bounds__(256) void mlp_kernel(
    const float* __restrict__ states,
    const float* __restrict__ l1_w, const float* __restrict__ l1_b,
    const float* __restrict__ l2_w, const float* __restrict__ l2_b,
    const float* __restrict__ l3_w, const float* __restrict__ l3_b,
    float* __restrict__ out)
{
    __shared__ float s_w[256 * 33];                  // 33.8 KB weight chunk
    __shared__ __align__(16) float s_x [RR * 64];
    __shared__ __align__(16) float s_a1[RR * 256];
    __shared__ __align__(16) float s_a2[RR * 260];   // pad: conflict-free l3

    const int tid = threadIdx.x;
    const int b0  = blockIdx.x * RR;

    const float4* st4 = (const float4*)(states + (size_t)b0 * 64);
    if (tid < RR * 16) ((float4*)s_x)[tid] = st4[tid];

    float acc[RR];

    // ================= layer 1: K=64, 2 k-chunks of 32 =================
    {
        const float bias = l1_b[tid];
        #pragma unroll
        for (int r = 0; r < RR; ++r) acc[r] = bias;

        for (int kc = 0; kc < 2; ++kc) {
            __syncthreads();
            #pragma unroll
            for (int i = 0; i < 8; ++i) {
                const int f  = tid + i * 256;
                const int j  = f >> 3;
                const int sg = f & 7;
                const float4 v = *(const float4*)(l1_w + j * 64 + kc * 32 + sg * 4);
                float* dst = &s_w[j * 33 + sg * 4];
                dst[0] = v.x; dst[1] = v.y; dst[2] = v.z; dst[3] = v.w;
            }
            __syncthreads();
            #pragma unroll
            for (int d4 = 0; d4 < 8; ++d4) {
                const float w0 = s_w[tid * 33 + d4 * 4 + 0];
                const float w1 = s_w[tid * 33 + d4 * 4 + 1];
                const float w2 = s_w[tid * 33 + d4 * 4 + 2];
                const float w3 = s_w[tid * 33 + d4 * 4 + 3];
                #pragma unroll
                for (int r = 0; r < RR; ++r) {
                    const float4 xv = *(const float4*)&s_x[r * 64 + kc * 32 + d4 * 4];
                    acc[r] += w0 * xv.x + w1 * xv.y + w2 * xv.z + w3 * xv.w;
                }
            }
        }
        #pragma unroll
        for (int r = 0; r < RR; ++r)
            s_a1[r * 256 + tid] = fmaxf(acc[r], 0.f);
    }

    // ================= layer 2: K=256, 8 k-chunks of 32 =================
    {
        const float bias = l2_b[tid];
        #pragma unroll
        for (int r = 0; r < RR; ++r) acc[r] = bias;

        for (int kc = 0; kc < 8; ++kc) {
            __syncthreads();
            #pragma unroll
            for (int i = 0; i < 8; ++i) {
                const int f  = tid + i * 256;
                const int j  = f >> 3;
                const int sg = f & 7;
                const float4 v = *(const float4*)(l2_w + j * 256 + kc * 32 + sg * 4);
                float* dst = &s_w[j * 33 + sg * 4];
                dst[0] = v.x; dst[1] = v.y; dst[2] = v.z; dst[3] = v.w;
            }
            __syncthreads();
            #pragma unroll
            for (int d4 = 0; d4 < 8; ++d4) {
                const float w0 = s_w[tid * 33 + d4 * 4 + 0];
                const float w1 = s_w[tid * 33 + d4 * 4 + 1];
                const float w2 = s_w[tid * 33 + d4 * 4 + 2];
                const float w3 = s_w[tid * 33 + d4 * 4 + 3];
                #pragma unroll
                for (int r = 0; r < RR; ++r) {
                    const float4 av = *(const float4*)&s_a1[r * 256 + kc * 32 + d4 * 4];
                    acc[r] += w0 * av.x + w1 * av.y + w2 * av.z + w3 * av.w;
                }
            }
        }
        #pragma unroll
        for (int r = 0; r < RR; ++r)
            s_a2[r * 260 + tid] = fmaxf(acc[r], 0.f);
    }
    __syncthreads();

    // ================= layer 3 + sigmoid =================
    if (tid < RR * 8) {
        const int r = tid >> 3, o = tid & 7;
        float a = l3_b[o];
        const float4* wr4 = (const float4*)(l3_w + o * 256);
        const float4* a4  = (const float4*)&s_a2[r * 260];
        #pragma unroll 8
        for (int k = 0; k < 64; ++k) {
            const float4 av = a4[k];
            const float4 wv = wr4[k];
            a += av.x * wv.x + av.y * wv.y + av.z * wv.z + av.w * wv.w;
        }
        out[(size_t)(b0 + r) * 8 + o] = 1.f / (1.f + __expf(-a)); // MAX_ACTION=1
    }
}

// ---------------------------------------------------------------------------
extern "C" void kernel_launch(void* const* d_in, const int* in_sizes, int n_in,
                              void* d_out, int out_size, void* d_ws, size_t ws_size,
                              hipStream_t stream)
{
    const float* gs    = (const float*)d_in[0];
    const float* ls    = (const float*)d_in[1];
    const float* W_w   = (const float*)d_in[2];
    const float* W_b   = (const float*)d_in[3];
    const float* U_w   = (const float*)d_in[4];
    const float* U_b   = (const float*)d_in[5];
    const float* att_w = (const float*)d_in[6];
    const float* att_b = (const float*)d_in[7];
    const float* l1_w  = (const float*)d_in[8];
    const float* l1_b  = (const float*)d_in[9];
    const float* l2_w  = (const float*)d_in[10];
    const float* l2_b  = (const float*)d_in[11];
    const float* l3_w  = (const float*)d_in[12];
    const float* l3_b  = (const float*)d_in[13];

    float* states = (float*)d_ws;            // B*64 floats = 1 MB scratch

    pool_kernel<<<BB, 256, 0, stream>>>(
        gs, ls, W_w, W_b, U_w, U_b, att_w, att_b, states);
    mlp_kernel<<<BB / RR, 256, 0, stream>>>(
        states, l1_w, l1_b, l2_w, l2_b, l3_w, l3_b, (float*)d_out);
}